// Round 6
// baseline (1877.389 us; speedup 1.0000x reference)
//
#include <hip/hip_runtime.h>
#include <math.h>
#include <stdint.h>

#define TOKENS 32768
#define DM 2048
#define DH 1024
#define NE 16
#define BM 128
#define BN 512
#define NPASS 2
#define NSTAGE 64          // DM / 32
#define TAU 4e-3f

// output layout (floats): gates[T*2] | indices[T*2] | probs[T*16]
#define OFF_IDX  (TOKENS * 2)
#define OFF_PROB (TOKENS * 4)

// ws layout (bytes): [0] cnt | [1024] list | [132096] wimg (4 MB fp16 image)
#define WS_LIST 1024
#define WS_WT   132096
#define WIMG_BYTES ((size_t)NSTAGE * NPASS * 32768)          // 4 MB
#define WS_NEEDED ((size_t)WS_WT + WIMG_BYTES)

typedef _Float16 f16x8 __attribute__((ext_vector_type(8)));
typedef short    bf16x8 __attribute__((ext_vector_type(8)));
typedef float    f32x16 __attribute__((ext_vector_type(16)));

static __device__ __forceinline__ void gload_lds16(const void* g, void* l) {
    __builtin_amdgcn_global_load_lds(
        (const __attribute__((address_space(1))) void*)g,
        (__attribute__((address_space(3))) void*)l, 16, 0, 0);
}

// ---------------- prep: W1 fp32 -> fp16 image, exact per-stage LDS byte image ----------------
// stage (s,p) image (32 KB): [q 0..3][n 0..511][8 fp16], where chunk q holds k = s*32+q*8..+7.
__global__ __launch_bounds__(256)
void prep_w16(const float* __restrict__ W1, char* __restrict__ wimg) {
    int u = blockIdx.x * 256 + threadIdx.x;    // 262144 16-B units
    int n = u & 511;
    int q = (u >> 9) & 3;
    int p = (u >> 11) & 1;
    int s = u >> 12;
    const float* src = W1 + (size_t)(s * 32 + q * 8) * DH + p * 512 + n;
    f16x8 v;
    #pragma unroll
    for (int j = 0; j < 8; ++j)
        v[j] = (_Float16)src[(size_t)j * DH];
    *(f16x8*)(wimg + (size_t)u * 16) = v;
}

// ---------------- fused GEMM1(fp16 MFMA) + GEMM2(fp32 VALU) + softmax + top2 + flag ----------------
__global__ __launch_bounds__(512, 2)
void router16(const float* __restrict__ x, const char* __restrict__ wimg,
              const float* __restrict__ b1, const float* __restrict__ W2,
              const float* __restrict__ b2, float* __restrict__ out,
              int* __restrict__ cnt, int* __restrict__ list)
{
    __shared__ __align__(16) char xsmem[2][8192];    // A dbuf: [q][m][8 fp16]
    __shared__ __align__(16) char bsmem[2][32768];   // B dbuf: [q][n][8 fp16]
    __shared__ float w2t[NE * 128];                  // 8 KB
    __shared__ float ls[BM * 17];                    // padded logits

    float* h_lds = (float*)&bsmem[0][0];             // [128][128] fp32, reused
    float* lsred = (float*)&bsmem[0][0];             // [2048][4], reused

    const int tid  = threadIdx.x;
    const int wid  = tid >> 6;
    const int lane = tid & 63;
    const int l31  = lane & 31;
    const int lh   = lane >> 5;
    const int wm   = wid >> 2;           // 0..1
    const int wn   = wid & 3;            // 0..3
    const int m0   = blockIdx.x * BM;

    const int tq  = tid & 31;
    const int egq = (tid >> 5) & 3;
    const int ns  = tid >> 7;

    const int arow = tid >> 2, kq = tid & 3;   // A staging: row 0..127, chunk 0..3

    float lacc[4][4];
    #pragma unroll
    for (int i = 0; i < 4; ++i)
        #pragma unroll
        for (int e = 0; e < 4; ++e) lacc[i][e] = 0.f;

    for (int p = 0; p < NPASS; ++p) {
        f32x16 acc[2][4];
        #pragma unroll
        for (int mf = 0; mf < 2; ++mf)
            #pragma unroll
            for (int nf = 0; nf < 4; ++nf)
                #pragma unroll
                for (int q = 0; q < 16; ++q) acc[mf][nf][q] = 0.f;

        // ---- prologue: stage s=0 into buf 0 ----
        {
            const char* sb = wimg + ((size_t)(0 * 2 + p) << 15);
            #pragma unroll
            for (int i = 0; i < 4; ++i)
                gload_lds16(sb + (wid << 12) + (i << 10) + (lane << 4),
                            &bsmem[0][(wid << 12) + (i << 10)]);
            const float* xp = x + (size_t)(m0 + arow) * DM + kq * 8;
            float4 v0 = *(const float4*)xp;
            float4 v1 = *(const float4*)(xp + 4);
            f16x8 av;
            av[0] = (_Float16)v0.x; av[1] = (_Float16)v0.y;
            av[2] = (_Float16)v0.z; av[3] = (_Float16)v0.w;
            av[4] = (_Float16)v1.x; av[5] = (_Float16)v1.y;
            av[6] = (_Float16)v1.z; av[7] = (_Float16)v1.w;
            *(f16x8*)(&xsmem[0][kq * 2048 + arow * 16]) = av;
        }
        __syncthreads();   // vmcnt+lgkm drained: stage 0 visible

        for (int s = 0; s < NSTAGE; ++s) {
            const int cur = s & 1;
            float4 xr0, xr1;
            // ---- issue next-stage loads BEFORE compute (latency hides under MFMA) ----
            if (s < NSTAGE - 1) {
                const char* sb = wimg + ((size_t)((s + 1) * 2 + p) << 15);
                #pragma unroll
                for (int i = 0; i < 4; ++i)
                    gload_lds16(sb + (wid << 12) + (i << 10) + (lane << 4),
                                &bsmem[cur ^ 1][(wid << 12) + (i << 10)]);
                const float* xp = x + (size_t)(m0 + arow) * DM + (s + 1) * 32 + kq * 8;
                xr0 = *(const float4*)xp;
                xr1 = *(const float4*)(xp + 4);
            }
            // ---- compute stage s: 2 ksteps x 2x4 MFMA, conflict-free c-major reads ----
            #pragma unroll
            for (int ks = 0; ks < 2; ++ks) {
                const int q = ks * 2 + lh;
                f16x8 af[2], bfr[4];
                #pragma unroll
                for (int mf = 0; mf < 2; ++mf)
                    af[mf] = *(const f16x8*)(&xsmem[cur][q * 2048 + (wm * 64 + mf * 32 + l31) * 16]);
                #pragma unroll
                for (int nf = 0; nf < 4; ++nf)
                    bfr[nf] = *(const f16x8*)(&bsmem[cur][q * 8192 + (wn * 128 + nf * 32 + l31) * 16]);
                #pragma unroll
                for (int mf = 0; mf < 2; ++mf)
                    #pragma unroll
                    for (int nf = 0; nf < 4; ++nf)
                        acc[mf][nf] = __builtin_amdgcn_mfma_f32_32x32x16_f16(af[mf], bfr[nf], acc[mf][nf], 0, 0, 0);
            }
            // ---- write-late: A tile for s+1 into the other buffer ----
            if (s < NSTAGE - 1) {
                f16x8 av;
                av[0] = (_Float16)xr0.x; av[1] = (_Float16)xr0.y;
                av[2] = (_Float16)xr0.z; av[3] = (_Float16)xr0.w;
                av[4] = (_Float16)xr1.x; av[5] = (_Float16)xr1.y;
                av[6] = (_Float16)xr1.z; av[7] = (_Float16)xr1.w;
                *(f16x8*)(&xsmem[cur ^ 1][kq * 2048 + arow * 16]) = av;
            }
            __syncthreads();  // drains vmcnt (B DMA landed) + lgkm (A write visible)
        }

        // ---- pass epilogue: bias+relu -> h chunks, fused GEMM2 (VALU, fp32) ----
        for (int ch = 0; ch < 4; ++ch) {
            __syncthreads();
            if (wn == ch) {
                #pragma unroll
                for (int nf = 0; nf < 4; ++nf) {
                    int col = nf * 32 + l31;
                    float bb = b1[p * BN + ch * 128 + col];
                    #pragma unroll
                    for (int mf = 0; mf < 2; ++mf)
                        #pragma unroll
                        for (int r = 0; r < 16; ++r) {
                            int row = wm * 64 + mf * 32 + (r & 3) + 8 * (r >> 2) + 4 * lh;
                            h_lds[row * 128 + col] = fmaxf(acc[mf][nf][r] + bb, 0.f);
                        }
                }
            }
            #pragma unroll
            for (int q = 0; q < 4; ++q) {
                int i = tid * 4 + q;
                int nn = i >> 4, e = i & 15;
                w2t[e * 128 + nn] = W2[(size_t)(p * BN + ch * 128 + nn) * NE + e];
            }
            __syncthreads();
            for (int nn = 0; nn < 32; ++nn) {
                int nL = ns * 32 + ((nn + tq) & 31);     // staggered: conflict-free
                float hv[4], wv[4];
                #pragma unroll
                for (int i = 0; i < 4; ++i) hv[i] = h_lds[(tq * 4 + i) * 128 + nL];
                #pragma unroll
                for (int e = 0; e < 4; ++e) wv[e] = w2t[(egq * 4 + e) * 128 + nL];
                #pragma unroll
                for (int i = 0; i < 4; ++i)
                    #pragma unroll
                    for (int e = 0; e < 4; ++e)
                        lacc[i][e] = fmaf(hv[i], wv[e], lacc[i][e]);
            }
        }
        __syncthreads();  // protect bsmem before next-pass prologue DMA
    }

    // ---- reduce partial logits over ns slices ----
    __syncthreads();
    #pragma unroll
    for (int i = 0; i < 4; ++i)
        #pragma unroll
        for (int e = 0; e < 4; ++e)
            lsred[((tq * 4 + i) * 16 + egq * 4 + e) * 4 + ns] = lacc[i][e];
    __syncthreads();
    #pragma unroll
    for (int q = 0; q < 4; ++q) {
        int idx = tid * 4 + q;
        int t = idx >> 4, e = idx & 15;
        ls[t * 17 + e] = lsred[idx * 4 + 0] + lsred[idx * 4 + 1] +
                         lsred[idx * 4 + 2] + lsred[idx * 4 + 3] + b2[e];
    }
    __syncthreads();

    // ---- softmax + top2 + flag ----
    if (tid < BM) {
        int t = tid;
        float l[NE]; float mx = -1e30f;
        #pragma unroll
        for (int e = 0; e < NE; ++e) { l[e] = ls[t * 17 + e]; mx = fmaxf(mx, l[e]); }
        float pb[NE]; float ssum = 0.f;
        #pragma unroll
        for (int e = 0; e < NE; ++e) { pb[e] = expf(l[e] - mx); ssum += pb[e]; }
        float inv = 1.f / ssum;
        #pragma unroll
        for (int e = 0; e < NE; ++e) pb[e] *= inv;

        int i1 = 0; float p1 = pb[0];
        #pragma unroll
        for (int e = 1; e < NE; ++e) if (pb[e] > p1) { p1 = pb[e]; i1 = e; }
        int i2 = -1; float p2 = -1.f;
        #pragma unroll
        for (int e = 0; e < NE; ++e) if (e != i1 && pb[e] > p2) { p2 = pb[e]; i2 = e; }
        float p3 = -1.f;
        #pragma unroll
        for (int e = 0; e < NE; ++e) if (e != i1 && e != i2 && pb[e] > p3) p3 = pb[e];

        float denom = p1 + p2 + 1e-8f;
        size_t gt = (size_t)(m0 + t);
        out[gt * 2 + 0] = p1 / denom;
        out[gt * 2 + 1] = p2 / denom;
        out[OFF_IDX + gt * 2 + 0] = (float)i1;
        out[OFF_IDX + gt * 2 + 1] = (float)i2;
        #pragma unroll
        for (int e = 0; e < NE; ++e) out[OFF_PROB + gt * 16 + e] = pb[e];

        if (p1 - p2 < TAU || p2 - p3 < TAU) {
            int k = atomicAdd(cnt, 1);
            list[k] = m0 + t;
        }
    }
}

// ---------------- fallback (ws too small): R4-proven on-the-fly bf16 3-term path ----------------
__global__ __launch_bounds__(512, 2)
void router_fb(const float* __restrict__ x, const float* __restrict__ W1,
               const float* __restrict__ b1, const float* __restrict__ W2,
               const float* __restrict__ b2, float* __restrict__ out,
               int* __restrict__ cnt, int* __restrict__ list)
{
    __shared__ short xs[BM * 64];
    __shared__ short bs[BN * 64];
    __shared__ float w2t[NE * 128];
    __shared__ float ls[BM * 17];

    float* h_lds = (float*)bs;
    float* lsred = (float*)bs;

    const int tid  = threadIdx.x;
    const int wid  = tid >> 6;
    const int lane = tid & 63;
    const int l31  = lane & 31;
    const int lh   = lane >> 5;
    const int sg   = lane & 7;
    const int wm   = wid >> 2;
    const int wn   = wid & 3;
    const int m0   = blockIdx.x * BM;

    const int tq  = tid & 31;
    const int egq = (tid >> 5) & 3;
    const int ns  = tid >> 7;

    float lacc[4][4];
    #pragma unroll
    for (int i = 0; i < 4; ++i)
        #pragma unroll
        for (int e = 0; e < 4; ++e) lacc[i][e] = 0.f;

    const int arow = tid >> 2, kq = tid & 3;
    const int asig = arow & 7;
    const int nloc = (wid << 6) + lane;
    const int sgl  = lane & 7;

    for (int p = 0; p < NPASS; ++p) {
        f32x16 acc[2][4];
        #pragma unroll
        for (int mf = 0; mf < 2; ++mf)
            #pragma unroll
            for (int nf = 0; nf < 4; ++nf)
                #pragma unroll
                for (int q = 0; q < 16; ++q) acc[mf][nf][q] = 0.f;

        for (int s = 0; s < NSTAGE; ++s) {
            __syncthreads();
            {
                const float* wp = W1 + (size_t)(s * 32) * DH + p * BN + nloc;
                short* rb = bs + nloc * 64;
                #pragma unroll
                for (int h = 0; h < 2; ++h) {
                    float f[16];
                    #pragma unroll
                    for (int j = 0; j < 16; ++j)
                        f[j] = wp[(size_t)(h * 16 + j) * DH];
                    uint32_t hd[8], ld_[8];
                    #pragma unroll
                    for (int q = 0; q < 8; ++q) {
                        uint32_t u0 = __float_as_uint(f[2 * q]);
                        uint32_t u1 = __float_as_uint(f[2 * q + 1]);
                        hd[q] = (u0 >> 16) | (u1 & 0xFFFF0000u);
                        float r0 = f[2 * q]     - __uint_as_float(u0 & 0xFFFF0000u);
                        float r1 = f[2 * q + 1] - __uint_as_float(u1 & 0xFFFF0000u);
                        ld_[q] = (__float_as_uint(r0) >> 16) | (__float_as_uint(r1) & 0xFFFF0000u);
                    }
                    *(int4*)(rb + (((2 * h + 0) ^ sgl) << 3)) = make_int4(hd[0], hd[1], hd[2], hd[3]);
                    *(int4*)(rb + (((2 * h + 1) ^ sgl) << 3)) = make_int4(hd[4], hd[5], hd[6], hd[7]);
                    *(int4*)(rb + (((4 + 2 * h + 0) ^ sgl) << 3)) = make_int4(ld_[0], ld_[1], ld_[2], ld_[3]);
                    *(int4*)(rb + (((4 + 2 * h + 1) ^ sgl) << 3)) = make_int4(ld_[4], ld_[5], ld_[6], ld_[7]);
                }
            }
            {
                const float* xp = x + (size_t)(m0 + arow) * DM + s * 32 + kq * 8;
                float4 v0 = *(const float4*)xp;
                float4 v1 = *(const float4*)(xp + 4);
                float f[8] = {v0.x, v0.y, v0.z, v0.w, v1.x, v1.y, v1.z, v1.w};
                uint32_t hd[4], ld_[4];
                #pragma unroll
                for (int q = 0; q < 4; ++q) {
                    uint32_t u0 = __float_as_uint(f[2 * q]);
                    uint32_t u1 = __float_as_uint(f[2 * q + 1]);
                    hd[q] = (u0 >> 16) | (u1 & 0xFFFF0000u);
                    float r0 = f[2 * q]     - __uint_as_float(u0 & 0xFFFF0000u);
                    float r1 = f[2 * q + 1] - __uint_as_float(u1 & 0xFFFF0000u);
                    ld_[q] = (__float_as_uint(r0) >> 16) | (__float_as_uint(r1) & 0xFFFF0000u);
                }
                short* ra = xs + arow * 64;
                *(int4*)(ra + ((kq ^ asig) << 3))       = make_int4(hd[0], hd[1], hd[2], hd[3]);
                *(int4*)(ra + (((4 + kq) ^ asig) << 3)) = make_int4(ld_[0], ld_[1], ld_[2], ld_[3]);
            }
            __syncthreads();
            #pragma unroll
            for (int ks = 0; ks < 2; ++ks) {
                bf16x8 a0[2], a1[2], b0[4], b1f[4];
                #pragma unroll
                for (int mf = 0; mf < 2; ++mf) {
                    int base = (wm * 64 + mf * 32 + l31) * 64;
                    a0[mf] = *(const bf16x8*)(xs + base + (((ks * 2 + lh)) ^ sg) * 8);
                    a1[mf] = *(const bf16x8*)(xs + base + (((4 + ks * 2 + lh)) ^ sg) * 8);
                }
                #pragma unroll
                for (int nf = 0; nf < 4; ++nf) {
                    int base = (wn * 128 + nf * 32 + l31) * 64;
                    b0[nf]  = *(const bf16x8*)(bs + base + (((ks * 2 + lh)) ^ sg) * 8);
                    b1f[nf] = *(const bf16x8*)(bs + base + (((4 + ks * 2 + lh)) ^ sg) * 8);
                }
                #pragma unroll
                for (int mf = 0; mf < 2; ++mf)
                    #pragma unroll
                    for (int nf = 0; nf < 4; ++nf) {
                        acc[mf][nf] = __builtin_amdgcn_mfma_f32_32x32x16_bf16(a0[mf], b0[nf],  acc[mf][nf], 0, 0, 0);
                        acc[mf][nf] = __builtin_amdgcn_mfma_f32_32x32x16_bf16(a0[mf], b1f[nf], acc[mf][nf], 0, 0, 0);
                        acc[mf][nf] = __builtin_amdgcn_mfma_f32_32x32x16_bf16(a1[mf], b0[nf],  acc[mf][nf], 0, 0, 0);
                    }
            }
        }

        for (int ch = 0; ch < 4; ++ch) {
            __syncthreads();
            if (wn == ch) {
                #pragma unroll
                for (int nf = 0; nf < 4; ++nf) {
                    int col = nf * 32 + l31;
                    float bb = b1[p * BN + ch * 128 + col];
                    #pragma unroll
                    for (int mf = 0; mf < 2; ++mf)
                        #pragma unroll
                        for (int r = 0; r < 16; ++r) {
                            int row = wm * 64 + mf * 32 + (r & 3) + 8 * (r >> 2) + 4 * lh;
                            h_lds[row * 128 + col] = fmaxf(acc[mf][nf][r] + bb, 0.f);
                        }
                }
            }
            #pragma unroll
            for (int q = 0; q < 4; ++q) {
                int i = tid * 4 + q;
                int nn = i >> 4, e = i & 15;
                w2t[e * 128 + nn] = W2[(size_t)(p * BN + ch * 128 + nn) * NE + e];
            }
            __syncthreads();
            for (int nn = 0; nn < 32; ++nn) {
                int nL = ns * 32 + ((nn + tq) & 31);
                float hv[4], wv[4];
                #pragma unroll
                for (int i = 0; i < 4; ++i) hv[i] = h_lds[(tq * 4 + i) * 128 + nL];
                #pragma unroll
                for (int e = 0; e < 4; ++e) wv[e] = w2t[(egq * 4 + e) * 128 + nL];
                #pragma unroll
                for (int i = 0; i < 4; ++i)
                    #pragma unroll
                    for (int e = 0; e < 4; ++e)
                        lacc[i][e] = fmaf(hv[i], wv[e], lacc[i][e]);
            }
        }
    }

    __syncthreads();
    #pragma unroll
    for (int i = 0; i < 4; ++i)
        #pragma unroll
        for (int e = 0; e < 4; ++e)
            lsred[((tq * 4 + i) * 16 + egq * 4 + e) * 4 + ns] = lacc[i][e];
    __syncthreads();
    #pragma unroll
    for (int q = 0; q < 4; ++q) {
        int idx = tid * 4 + q;
        int t = idx >> 4, e = idx & 15;
        ls[t * 17 + e] = lsred[idx * 4 + 0] + lsred[idx * 4 + 1] +
                         lsred[idx * 4 + 2] + lsred[idx * 4 + 3] + b2[e];
    }
    __syncthreads();

    if (tid < BM) {
        int t = tid;
        float l[NE]; float mx = -1e30f;
        #pragma unroll
        for (int e = 0; e < NE; ++e) { l[e] = ls[t * 17 + e]; mx = fmaxf(mx, l[e]); }
        float pb[NE]; float ssum = 0.f;
        #pragma unroll
        for (int e = 0; e < NE; ++e) { pb[e] = expf(l[e] - mx); ssum += pb[e]; }
        float inv = 1.f / ssum;
        #pragma unroll
        for (int e = 0; e < NE; ++e) pb[e] *= inv;

        int i1 = 0; float p1 = pb[0];
        #pragma unroll
        for (int e = 1; e < NE; ++e) if (pb[e] > p1) { p1 = pb[e]; i1 = e; }
        int i2 = -1; float p2 = -1.f;
        #pragma unroll
        for (int e = 0; e < NE; ++e) if (e != i1 && pb[e] > p2) { p2 = pb[e]; i2 = e; }
        float p3 = -1.f;
        #pragma unroll
        for (int e = 0; e < NE; ++e) if (e != i1 && e != i2 && pb[e] > p3) p3 = pb[e];

        float denom = p1 + p2 + 1e-8f;
        size_t gt = (size_t)(m0 + t);
        out[gt * 2 + 0] = p1 / denom;
        out[gt * 2 + 1] = p2 / denom;
        out[OFF_IDX + gt * 2 + 0] = (float)i1;
        out[OFF_IDX + gt * 2 + 1] = (float)i2;
        #pragma unroll
        for (int e = 0; e < NE; ++e) out[OFF_PROB + gt * 16 + e] = pb[e];

        if (p1 - p2 < TAU || p2 - p3 < TAU) {
            int k = atomicAdd(cnt, 1);
            list[k] = m0 + t;
        }
    }
}

// ---------------- exact fp32 repair: 4 tokens/block streaming GEMM ----------------
__global__ __launch_bounds__(256, 3)
void repair4(const float* __restrict__ x, const float* __restrict__ W1,
             const float* __restrict__ b1, const float* __restrict__ W2,
             const float* __restrict__ b2, float* __restrict__ out,
             const int* __restrict__ cnt, const int* __restrict__ list)
{
    __shared__ float xsh[4][DM];
    __shared__ float hsh[4][DH];
    __shared__ float red[256];
    __shared__ float lg[4][NE];
    __shared__ int   tokid[4];

    const int tid  = threadIdx.x;
    const int nrep = cnt[0];

    for (int g = blockIdx.x; g * 4 < nrep; g += gridDim.x) {
        __syncthreads();
        if (tid < 4) {
            int j = g * 4 + tid;
            tokid[tid] = list[j < nrep ? j : 0];
        }
        __syncthreads();

        #pragma unroll
        for (int i = 0; i < 8; ++i) {
            int slot = tid + i * 256;
            int t = slot >> 9, c = slot & 511;
            *(float4*)(&xsh[t][c * 4]) =
                *(const float4*)(x + (size_t)tokid[t] * DM + c * 4);
        }
        __syncthreads();

        float acc[4][4];
        #pragma unroll
        for (int t = 0; t < 4; ++t)
            #pragma unroll
            for (int q = 0; q < 4; ++q) acc[t][q] = 0.f;

        for (int k4 = 0; k4 < DM / 4; ++k4) {
            float4 xv[4];
            #pragma unroll
            for (int t = 0; t < 4; ++t)
                xv[t] = *(const float4*)(&xsh[t][k4 * 4]);
            #pragma unroll
            for (int kk = 0; kk < 4; ++kk) {
                const float4 w = *(const float4*)(W1 + (size_t)(k4 * 4 + kk) * DH + tid * 4);
                #pragma unroll
                for (int t = 0; t < 4; ++t) {
                    const float a = ((const float*)&xv[t])[kk];
                    acc[t][0] = fmaf(a, w.x, acc[t][0]);
                    acc[t][1] = fmaf(a, w.y, acc[t][1]);
                    acc[t][2] = fmaf(a, w.z, acc[t][2]);
                    acc[t][3] = fmaf(a, w.w, acc[t][3]);
                }
            }
        }

        {
            const float4 bv = *(const float4*)(b1 + tid * 4);
            #pragma unroll
            for (int t = 0; t < 4; ++t) {
                float4 h;
                h.x = fmaxf(acc[t][0] + bv.x, 0.f);
                h.y = fmaxf(acc[t][1] + bv.y, 0.f);
                h.z = fmaxf(acc[t][2] + bv.z, 0.f);
                h.w = fmaxf(acc[t][3] + bv.w, 0.f);
                *(float4*)(&hsh[t][tid * 4]) = h;
            }
        }
        __syncthreads();

        {
            const int e  = tid & 15;
            const int t  = (tid >> 4) & 3;
            const int sl = tid >> 6;
            float ps = 0.f;
            for (int q = 0; q < 256; ++q) {
                int n = sl * 256 + q;
                ps = fmaf(hsh[t][n], W2[n * NE + e], ps);
            }
            red[tid] = ps;
        }
        __syncthreads();
        if (tid < 64) {
            int t = tid >> 4, e = tid & 15;
            lg[t][e] = b2[e] + red[0 * 64 + t * 16 + e] + red[1 * 64 + t * 16 + e]
                             + red[2 * 64 + t * 16 + e] + red[3 * 64 + t * 16 + e];
        }
        __syncthreads();

        if (tid < 4 && g * 4 + tid < nrep) {
            const int t = tid;
            float l[NE]; float mx = -1e30f;
            #pragma unroll
            for (int e = 0; e < NE; ++e) { l[e] = lg[t][e]; mx = fmaxf(mx, l[e]); }
            float pb[NE]; float ssum = 0.f;
            #pragma unroll
            for (int e = 0; e < NE; ++e) { pb[e] = expf(l[e] - mx); ssum += pb[e]; }
            float inv = 1.f / ssum;
            #pragma unroll
            for (int e = 0; e < NE; ++e) pb[e] *= inv;

            int i1 = 0; float p1 = pb[0];
            #pragma unroll
            for (int e = 1; e < NE; ++e) if (pb[e] > p1) { p1 = pb[e]; i1 = e; }
            int i2 = -1; float p2 = -1.f;
            #pragma unroll
            for (int e = 0; e < NE; ++e) if (e != i1 && pb[e] > p2) { p2 = pb[e]; i2 = e; }
            float denom = p1 + p2 + 1e-8f;
            size_t gt = (size_t)tokid[t];
            out[gt * 2 + 0] = p1 / denom;
            out[gt * 2 + 1] = p2 / denom;
            out[OFF_IDX + gt * 2 + 0] = (float)i1;
            out[OFF_IDX + gt * 2 + 1] = (float)i2;
            #pragma unroll
            for (int e = 0; e < NE; ++e) out[OFF_PROB + gt * 16 + e] = pb[e];
        }
    }
}

extern "C" void kernel_launch(void* const* d_in, const int* in_sizes, int n_in,
                              void* d_out, int out_size, void* d_ws, size_t ws_size,
                              hipStream_t stream) {
    const float* x  = (const float*)d_in[0];
    const float* W1 = (const float*)d_in[1];
    const float* b1 = (const float*)d_in[2];
    const float* W2 = (const float*)d_in[3];
    const float* b2 = (const float*)d_in[4];
    float* out = (float*)d_out;

    int*  cnt  = (int*)d_ws;
    int*  list = (int*)((char*)d_ws + WS_LIST);
    char* wimg = (char*)d_ws + WS_WT;

    hipMemsetAsync(cnt, 0, sizeof(int), stream);
    if (ws_size >= WS_NEEDED) {
        hipLaunchKernelGGL(prep_w16, dim3(1024), dim3(256), 0, stream, W1, wimg);
        hipLaunchKernelGGL(router16, dim3(TOKENS / BM), dim3(512), 0, stream,
                           x, wimg, b1, W2, b2, out, cnt, list);
    } else {
        hipLaunchKernelGGL(router_fb, dim3(TOKENS / BM), dim3(512), 0, stream,
                           x, W1, b1, W2, b2, out, cnt, list);
    }
    hipLaunchKernelGGL(repair4, dim3(512), dim3(256), 0, stream,
                       x, W1, b1, W2, b2, out, cnt, list);
}

// Round 7
// 517.533 us; speedup vs baseline: 3.6276x; 3.6276x over previous
//
#include <hip/hip_runtime.h>
#include <math.h>
#include <stdint.h>

#define TOKENS 32768
#define DM 2048
#define DH 1024
#define NE 16
#define BM 128
#define BN 512
#define NPASS 2
#define BK 16
#define NSTAGE 128             // DM / BK
#define RT_TAU 5e-5f           // fp16-3term path (logit sigma ~1e-6, 50x margin)
#define FB_TAU 5e-4f           // bf16-3term fallback path
#define XSC 16.0f              // x pre-scale (2^4)
#define WSC 64.0f              // W pre-scale (2^6)
#define DESC (1.0f/1024.0f)    // acc descale (2^-10)

// output layout (floats): gates[T*2] | indices[T*2] | probs[T*16]
#define OFF_IDX  (TOKENS * 2)
#define OFF_PROB (TOKENS * 4)

// ws layout: [0] cnt | [1024] list (32768 int) | [132096] wimg (8 MB fp16 hi/lo image)
// repair partials alias wimg (used only after router finishes).
#define WS_LIST 1024
#define WS_WT   132096
#define WIMG_BYTES ((size_t)NSTAGE * NPASS * 32768)     // 8 MB
#define WS_NEEDED ((size_t)WS_WT + WIMG_BYTES)
#define RCAP 512               // fast-repair capacity (128 groups x 4 tokens)

typedef _Float16 f16x8 __attribute__((ext_vector_type(8)));
typedef _Float16 f16x4 __attribute__((ext_vector_type(4)));
typedef short    bf16x8 __attribute__((ext_vector_type(8)));
typedef float    f32x16 __attribute__((ext_vector_type(16)));

static __device__ __forceinline__ void gload_lds16(const void* g, void* l) {
    __builtin_amdgcn_global_load_lds(
        (const __attribute__((address_space(1))) void*)g,
        (__attribute__((address_space(3))) void*)l, 16, 0, 0);
}

// ---------------- prep: W1 -> per-stage LDS byte image: [q(2)][plane(2)][n(512)][8 fp16] ----------------
// stage index = s*2 + p; chunk q holds k = s*16 + q*8 .. +7; plane 0 = fp16(w*64), plane 1 = residual.
__global__ __launch_bounds__(256)
void prep_w16(const float* __restrict__ W1, char* __restrict__ wimg) {
    const int bid = blockIdx.x;            // 0..255 = s*2+p
    const int s = bid >> 1, p = bid & 1;
    char* img = wimg + ((size_t)bid << 15);
    const int tid = threadIdx.x;
    #pragma unroll
    for (int rep = 0; rep < 2; ++rep) {
        const int n = tid + rep * 256;
        float w[16];
        #pragma unroll
        for (int j = 0; j < 16; ++j)
            w[j] = W1[(size_t)(s * 16 + j) * DH + p * 512 + n] * WSC;
        #pragma unroll
        for (int q = 0; q < 2; ++q) {
            f16x8 hi, lo;
            #pragma unroll
            for (int j = 0; j < 8; ++j) {
                float ww = w[q * 8 + j];
                _Float16 h = (_Float16)ww;
                hi[j] = h;
                lo[j] = (_Float16)(ww - (float)h);
            }
            *(f16x8*)(img + ((q * 2 + 0) * 512 + n) * 16) = hi;
            *(f16x8*)(img + ((q * 2 + 1) * 512 + n) * 16) = lo;
        }
    }
}

// ---------------- fused GEMM1 (fp16 3-term MFMA) + GEMM2 (fp32) + softmax + top2 + flag ----------------
__global__ __launch_bounds__(512, 2)
void router16(const float* __restrict__ x, const char* __restrict__ wimg,
              const float* __restrict__ b1, const float* __restrict__ W2,
              const float* __restrict__ b2, float* __restrict__ out,
              int* __restrict__ cnt, int* __restrict__ list)
{
    __shared__ __align__(16) char xsmem[2][8192];    // A dbuf: [q][plane][m][16B]
    __shared__ __align__(16) char bsmem[2][32768];   // B dbuf: [q][plane][n][16B]
    __shared__ float w2t[NE * 128];                  // 8 KB
    __shared__ float ls[BM * 17];                    // padded logits

    float* h_lds = (float*)&bsmem[0][0];             // [128][128] fp32, reused (64 KB)
    float* lsred = (float*)&bsmem[0][0];             // [2048][4], reused

    const int tid  = threadIdx.x;
    const int wid  = tid >> 6;
    const int lane = tid & 63;
    const int l31  = lane & 31;
    const int lh   = lane >> 5;
    const int wm   = wid >> 2;            // 0..1
    const int wn   = wid & 3;             // 0..3
    const int m0   = blockIdx.x * BM;

    const int tq  = tid & 31;
    const int egq = (tid >> 5) & 3;
    const int ns  = tid >> 7;

    const int arow = tid >> 2, kq = tid & 3;    // A staging: row, k-quad
    const int q4 = kq >> 1, half = kq & 1;

    float lacc[4][4];
    #pragma unroll
    for (int i = 0; i < 4; ++i)
        #pragma unroll
        for (int e = 0; e < 4; ++e) lacc[i][e] = 0.f;

    for (int p = 0; p < NPASS; ++p) {
        f32x16 acc[2][4];
        #pragma unroll
        for (int mf = 0; mf < 2; ++mf)
            #pragma unroll
            for (int nf = 0; nf < 4; ++nf)
                #pragma unroll
                for (int q = 0; q < 16; ++q) acc[mf][nf][q] = 0.f;

        // ---- prologue: stage 0 into buf 0 ----
        {
            const char* img = wimg + ((size_t)(0 * 2 + p) << 15);
            #pragma unroll
            for (int i = 0; i < 4; ++i) {
                int seg = (wid << 2) + i;
                gload_lds16(img + (seg << 10) + (lane << 4), &bsmem[0][seg << 10]);
            }
            const float* xp = x + (size_t)(m0 + arow) * DM + kq * 4;
            float4 v = *(const float4*)xp;
            float f[4] = {v.x * XSC, v.y * XSC, v.z * XSC, v.w * XSC};
            f16x4 hi, lo;
            #pragma unroll
            for (int j = 0; j < 4; ++j) {
                _Float16 h = (_Float16)f[j];
                hi[j] = h;
                lo[j] = (_Float16)(f[j] - (float)h);
            }
            *(f16x4*)(&xsmem[0][((q4 * 2 + 0) * 128 + arow) * 16 + half * 8]) = hi;
            *(f16x4*)(&xsmem[0][((q4 * 2 + 1) * 128 + arow) * 16 + half * 8]) = lo;
        }
        __syncthreads();   // stage 0 visible (vmcnt+lgkm drained by barrier)

        for (int s = 0; s < NSTAGE; ++s) {
            const int cur = s & 1;
            float4 xr;
            // ---- issue next-stage B-DMA + x-load BEFORE compute (latency hides under MFMA) ----
            if (s < NSTAGE - 1) {
                const char* img = wimg + ((size_t)((s + 1) * 2 + p) << 15);
                #pragma unroll
                for (int i = 0; i < 4; ++i) {
                    int seg = (wid << 2) + i;
                    gload_lds16(img + (seg << 10) + (lane << 4), &bsmem[cur ^ 1][seg << 10]);
                }
                xr = *(const float4*)(x + (size_t)(m0 + arow) * DM + (s + 1) * BK + kq * 4);
            }
            // ---- compute stage s: q = lh; terms xh*wh + xh*wl + xl*wh ----
            {
                const int q = lh;
                const char* xb = &xsmem[cur][0];
                const char* bb = &bsmem[cur][0];
                f16x8 ah[2], al[2], bh[4], bl[4];
                #pragma unroll
                for (int mf = 0; mf < 2; ++mf) {
                    int m = wm * 64 + mf * 32 + l31;
                    ah[mf] = *(const f16x8*)(xb + ((q * 2 + 0) * 128 + m) * 16);
                    al[mf] = *(const f16x8*)(xb + ((q * 2 + 1) * 128 + m) * 16);
                }
                #pragma unroll
                for (int nf = 0; nf < 4; ++nf) {
                    int n = wn * 128 + nf * 32 + l31;
                    bh[nf] = *(const f16x8*)(bb + ((q * 2 + 0) * 512 + n) * 16);
                    bl[nf] = *(const f16x8*)(bb + ((q * 2 + 1) * 512 + n) * 16);
                }
                #pragma unroll
                for (int mf = 0; mf < 2; ++mf)
                    #pragma unroll
                    for (int nf = 0; nf < 4; ++nf) {
                        acc[mf][nf] = __builtin_amdgcn_mfma_f32_32x32x16_f16(ah[mf], bh[nf], acc[mf][nf], 0, 0, 0);
                        acc[mf][nf] = __builtin_amdgcn_mfma_f32_32x32x16_f16(ah[mf], bl[nf], acc[mf][nf], 0, 0, 0);
                        acc[mf][nf] = __builtin_amdgcn_mfma_f32_32x32x16_f16(al[mf], bh[nf], acc[mf][nf], 0, 0, 0);
                    }
            }
            // ---- write-late: A tile for s+1 ----
            if (s < NSTAGE - 1) {
                float f[4] = {xr.x * XSC, xr.y * XSC, xr.z * XSC, xr.w * XSC};
                f16x4 hi, lo;
                #pragma unroll
                for (int j = 0; j < 4; ++j) {
                    _Float16 h = (_Float16)f[j];
                    hi[j] = h;
                    lo[j] = (_Float16)(f[j] - (float)h);
                }
                *(f16x4*)(&xsmem[cur ^ 1][((q4 * 2 + 0) * 128 + arow) * 16 + half * 8]) = hi;
                *(f16x4*)(&xsmem[cur ^ 1][((q4 * 2 + 1) * 128 + arow) * 16 + half * 8]) = lo;
            }
            __syncthreads();
        }

        // ---- pass epilogue: descale + bias + relu -> h chunks, fused GEMM2 (fp32) ----
        for (int ch = 0; ch < 4; ++ch) {
            __syncthreads();
            if (wn == ch) {
                #pragma unroll
                for (int nf = 0; nf < 4; ++nf) {
                    int col = nf * 32 + l31;
                    float bb = b1[p * BN + ch * 128 + col];
                    #pragma unroll
                    for (int mf = 0; mf < 2; ++mf)
                        #pragma unroll
                        for (int r = 0; r < 16; ++r) {
                            int row = wm * 64 + mf * 32 + (r & 3) + 8 * (r >> 2) + 4 * lh;
                            h_lds[row * 128 + col] = fmaxf(acc[mf][nf][r] * DESC + bb, 0.f);
                        }
                }
            }
            #pragma unroll
            for (int q = 0; q < 4; ++q) {
                int i = tid * 4 + q;
                int nn = i >> 4, e = i & 15;
                w2t[e * 128 + nn] = W2[(size_t)(p * BN + ch * 128 + nn) * NE + e];
            }
            __syncthreads();
            for (int nn = 0; nn < 32; ++nn) {
                int nL = ns * 32 + ((nn + tq) & 31);
                float hv[4], wv[4];
                #pragma unroll
                for (int i = 0; i < 4; ++i) hv[i] = h_lds[(tq * 4 + i) * 128 + nL];
                #pragma unroll
                for (int e = 0; e < 4; ++e) wv[e] = w2t[(egq * 4 + e) * 128 + nL];
                #pragma unroll
                for (int i = 0; i < 4; ++i)
                    #pragma unroll
                    for (int e = 0; e < 4; ++e)
                        lacc[i][e] = fmaf(hv[i], wv[e], lacc[i][e]);
            }
        }
        __syncthreads();  // protect bsmem before next-pass prologue DMA
    }

    // ---- reduce partial logits ----
    __syncthreads();
    #pragma unroll
    for (int i = 0; i < 4; ++i)
        #pragma unroll
        for (int e = 0; e < 4; ++e)
            lsred[((tq * 4 + i) * 16 + egq * 4 + e) * 4 + ns] = lacc[i][e];
    __syncthreads();
    #pragma unroll
    for (int q = 0; q < 4; ++q) {
        int idx = tid * 4 + q;
        int t = idx >> 4, e = idx & 15;
        ls[t * 17 + e] = lsred[idx * 4 + 0] + lsred[idx * 4 + 1] +
                         lsred[idx * 4 + 2] + lsred[idx * 4 + 3] + b2[e];
    }
    __syncthreads();

    // ---- softmax + top2 + flag ----
    if (tid < BM) {
        int t = tid;
        float l[NE]; float mx = -1e30f;
        #pragma unroll
        for (int e = 0; e < NE; ++e) { l[e] = ls[t * 17 + e]; mx = fmaxf(mx, l[e]); }
        float pb[NE]; float ssum = 0.f;
        #pragma unroll
        for (int e = 0; e < NE; ++e) { pb[e] = expf(l[e] - mx); ssum += pb[e]; }
        float inv = 1.f / ssum;
        #pragma unroll
        for (int e = 0; e < NE; ++e) pb[e] *= inv;

        int i1 = 0; float p1 = pb[0];
        #pragma unroll
        for (int e = 1; e < NE; ++e) if (pb[e] > p1) { p1 = pb[e]; i1 = e; }
        int i2 = -1; float p2 = -1.f;
        #pragma unroll
        for (int e = 0; e < NE; ++e) if (e != i1 && pb[e] > p2) { p2 = pb[e]; i2 = e; }
        float p3 = -1.f;
        #pragma unroll
        for (int e = 0; e < NE; ++e) if (e != i1 && e != i2 && pb[e] > p3) p3 = pb[e];

        float denom = p1 + p2 + 1e-8f;
        size_t gt = (size_t)(m0 + t);
        out[gt * 2 + 0] = p1 / denom;
        out[gt * 2 + 1] = p2 / denom;
        out[OFF_IDX + gt * 2 + 0] = (float)i1;
        out[OFF_IDX + gt * 2 + 1] = (float)i2;
        #pragma unroll
        for (int e = 0; e < NE; ++e) out[OFF_PROB + gt * 16 + e] = pb[e];

        if (p1 - p2 < RT_TAU || p2 - p3 < RT_TAU) {
            int k = atomicAdd(cnt, 1);
            list[k] = m0 + t;
        }
    }
}

// ---------------- fast repair: split-k partials (128 groups x 4 k-slices) ----------------
__global__ __launch_bounds__(256, 4)
void repair_partial(const float* __restrict__ x, const float* __restrict__ W1,
                    const int* __restrict__ cnt, const int* __restrict__ list,
                    float* __restrict__ hpart)
{
    __shared__ float xsl[4][512];
    __shared__ int tokid[4];
    const int tid = threadIdx.x;
    int nrep = cnt[0]; if (nrep > RCAP) nrep = RCAP;
    const int g = blockIdx.x >> 2, ks = blockIdx.x & 3;
    if (g * 4 >= nrep) return;

    if (tid < 4) {
        int j = g * 4 + tid;
        tokid[tid] = list[j < nrep ? j : 0];
    }
    __syncthreads();
    #pragma unroll
    for (int i = 0; i < 2; ++i) {
        int slot = tid + i * 256;            // 512 float4 slots
        int t = slot >> 7, c = slot & 127;
        *(float4*)(&xsl[t][c * 4]) =
            *(const float4*)(x + (size_t)tokid[t] * DM + ks * 512 + c * 4);
    }
    __syncthreads();

    float acc[4][4];
    #pragma unroll
    for (int t = 0; t < 4; ++t)
        #pragma unroll
        for (int q = 0; q < 4; ++q) acc[t][q] = 0.f;

    for (int k4 = 0; k4 < 128; ++k4) {
        float4 xv[4];
        #pragma unroll
        for (int t = 0; t < 4; ++t) xv[t] = *(const float4*)(&xsl[t][k4 * 4]);
        #pragma unroll
        for (int kk = 0; kk < 4; ++kk) {
            const float4 w = *(const float4*)(W1 + (size_t)(ks * 512 + k4 * 4 + kk) * DH + tid * 4);
            #pragma unroll
            for (int t = 0; t < 4; ++t) {
                const float a = ((const float*)&xv[t])[kk];
                acc[t][0] = fmaf(a, w.x, acc[t][0]);
                acc[t][1] = fmaf(a, w.y, acc[t][1]);
                acc[t][2] = fmaf(a, w.z, acc[t][2]);
                acc[t][3] = fmaf(a, w.w, acc[t][3]);
            }
        }
    }
    #pragma unroll
    for (int t = 0; t < 4; ++t)
        *(float4*)(hpart + (size_t)(g * 16 + ks * 4 + t) * 1024 + tid * 4) =
            make_float4(acc[t][0], acc[t][1], acc[t][2], acc[t][3]);
}

__global__ __launch_bounds__(256, 2)
void repair_final(const float* __restrict__ hpart, const float* __restrict__ b1,
                  const float* __restrict__ W2, const float* __restrict__ b2,
                  float* __restrict__ out,
                  const int* __restrict__ cnt, const int* __restrict__ list)
{
    __shared__ float hsh[4][DH];     // 16 KB
    __shared__ float red[256];
    __shared__ float lg[4][NE];
    __shared__ int tokid[4];
    const int tid = threadIdx.x;
    int nrep = cnt[0]; if (nrep > RCAP) nrep = RCAP;
    const int g = blockIdx.x;
    if (g * 4 >= nrep) return;

    if (tid < 4) {
        int j = g * 4 + tid;
        tokid[tid] = list[j < nrep ? j : 0];
    }
    __syncthreads();
    #pragma unroll
    for (int i = 0; i < 4; ++i) {
        int slot = tid + i * 256;            // 1024 float4 slots
        int t = slot >> 8, c = slot & 255;
        float4 s0 = *(const float4*)(hpart + (size_t)(g * 16 + 0 * 4 + t) * 1024 + c * 4);
        float4 s1 = *(const float4*)(hpart + (size_t)(g * 16 + 1 * 4 + t) * 1024 + c * 4);
        float4 s2 = *(const float4*)(hpart + (size_t)(g * 16 + 2 * 4 + t) * 1024 + c * 4);
        float4 s3 = *(const float4*)(hpart + (size_t)(g * 16 + 3 * 4 + t) * 1024 + c * 4);
        float4 bv = *(const float4*)(b1 + c * 4);
        float4 h;
        h.x = fmaxf(s0.x + s1.x + s2.x + s3.x + bv.x, 0.f);
        h.y = fmaxf(s0.y + s1.y + s2.y + s3.y + bv.y, 0.f);
        h.z = fmaxf(s0.z + s1.z + s2.z + s3.z + bv.z, 0.f);
        h.w = fmaxf(s0.w + s1.w + s2.w + s3.w + bv.w, 0.f);
        *(float4*)(&hsh[t][c * 4]) = h;
    }
    __syncthreads();
    {
        const int e  = tid & 15;
        const int t  = (tid >> 4) & 3;
        const int sl = tid >> 6;
        float ps = 0.f;
        for (int q = 0; q < 256; ++q) {
            int n = sl * 256 + q;
            ps = fmaf(hsh[t][n], W2[n * NE + e], ps);
        }
        red[tid] = ps;
    }
    __syncthreads();
    if (tid < 64) {
        int t = tid >> 4, e = tid & 15;
        lg[t][e] = b2[e] + red[0 * 64 + t * 16 + e] + red[1 * 64 + t * 16 + e]
                         + red[2 * 64 + t * 16 + e] + red[3 * 64 + t * 16 + e];
    }
    __syncthreads();
    if (tid < 4 && g * 4 + tid < nrep) {
        const int t = tid;
        float l[NE]; float mx = -1e30f;
        #pragma unroll
        for (int e = 0; e < NE; ++e) { l[e] = lg[t][e]; mx = fmaxf(mx, l[e]); }
        float pb[NE]; float ssum = 0.f;
        #pragma unroll
        for (int e = 0; e < NE; ++e) { pb[e] = expf(l[e] - mx); ssum += pb[e]; }
        float inv = 1.f / ssum;
        #pragma unroll
        for (int e = 0; e < NE; ++e) pb[e] *= inv;
        int i1 = 0; float p1 = pb[0];
        #pragma unroll
        for (int e = 1; e < NE; ++e) if (pb[e] > p1) { p1 = pb[e]; i1 = e; }
        int i2 = -1; float p2 = -1.f;
        #pragma unroll
        for (int e = 0; e < NE; ++e) if (e != i1 && pb[e] > p2) { p2 = pb[e]; i2 = e; }
        float denom = p1 + p2 + 1e-8f;
        size_t gt = (size_t)tokid[t];
        out[gt * 2 + 0] = p1 / denom;
        out[gt * 2 + 1] = p2 / denom;
        out[OFF_IDX + gt * 2 + 0] = (float)i1;
        out[OFF_IDX + gt * 2 + 1] = (float)i2;
        #pragma unroll
        for (int e = 0; e < NE; ++e) out[OFF_PROB + gt * 16 + e] = pb[e];
    }
}

// ---------------- repair4: full exact recompute, 4 tokens/group (overflow backstop + fallback) ----------------
__global__ __launch_bounds__(256, 3)
void repair4(const float* __restrict__ x, const float* __restrict__ W1,
             const float* __restrict__ b1, const float* __restrict__ W2,
             const float* __restrict__ b2, float* __restrict__ out,
             const int* __restrict__ cnt, const int* __restrict__ list, int g0)
{
    __shared__ float xsh[4][DM];
    __shared__ float hsh[4][DH];
    __shared__ float red[256];
    __shared__ float lg[4][NE];
    __shared__ int   tokid[4];

    const int tid  = threadIdx.x;
    const int nrep = cnt[0];

    for (int g = g0 + blockIdx.x; g * 4 < nrep; g += gridDim.x) {
        __syncthreads();
        if (tid < 4) {
            int j = g * 4 + tid;
            tokid[tid] = list[j < nrep ? j : 0];
        }
        __syncthreads();
        #pragma unroll
        for (int i = 0; i < 8; ++i) {
            int slot = tid + i * 256;
            int t = slot >> 9, c = slot & 511;
            *(float4*)(&xsh[t][c * 4]) =
                *(const float4*)(x + (size_t)tokid[t] * DM + c * 4);
        }
        __syncthreads();

        float acc[4][4];
        #pragma unroll
        for (int t = 0; t < 4; ++t)
            #pragma unroll
            for (int q = 0; q < 4; ++q) acc[t][q] = 0.f;

        for (int k4 = 0; k4 < DM / 4; ++k4) {
            float4 xv[4];
            #pragma unroll
            for (int t = 0; t < 4; ++t) xv[t] = *(const float4*)(&xsh[t][k4 * 4]);
            #pragma unroll
            for (int kk = 0; kk < 4; ++kk) {
                const float4 w = *(const float4*)(W1 + (size_t)(k4 * 4 + kk) * DH + tid * 4);
                #pragma unroll
                for (int t = 0; t < 4; ++t) {
                    const float a = ((const float*)&xv[t])[kk];
                    acc[t][0] = fmaf(a, w.x, acc[t][0]);
                    acc[t][1] = fmaf(a, w.y, acc[t][1]);
                    acc[t][2] = fmaf(a, w.z, acc[t][2]);
                    acc[t][3] = fmaf(a, w.w, acc[t][3]);
                }
            }
        }
        {
            const float4 bv = *(const float4*)(b1 + tid * 4);
            #pragma unroll
            for (int t = 0; t < 4; ++t) {
                float4 h;
                h.x = fmaxf(acc[t][0] + bv.x, 0.f);
                h.y = fmaxf(acc[t][1] + bv.y, 0.f);
                h.z = fmaxf(acc[t][2] + bv.z, 0.f);
                h.w = fmaxf(acc[t][3] + bv.w, 0.f);
                *(float4*)(&hsh[t][tid * 4]) = h;
            }
        }
        __syncthreads();
        {
            const int e  = tid & 15;
            const int t  = (tid >> 4) & 3;
            const int sl = tid >> 6;
            float ps = 0.f;
            for (int q = 0; q < 256; ++q) {
                int n = sl * 256 + q;
                ps = fmaf(hsh[t][n], W2[n * NE + e], ps);
            }
            red[tid] = ps;
        }
        __syncthreads();
        if (tid < 64) {
            int t = tid >> 4, e = tid & 15;
            lg[t][e] = b2[e] + red[0 * 64 + t * 16 + e] + red[1 * 64 + t * 16 + e]
                             + red[2 * 64 + t * 16 + e] + red[3 * 64 + t * 16 + e];
        }
        __syncthreads();
        if (tid < 4 && g * 4 + tid < nrep) {
            const int t = tid;
            float l[NE]; float mx = -1e30f;
            #pragma unroll
            for (int e = 0; e < NE; ++e) { l[e] = lg[t][e]; mx = fmaxf(mx, l[e]); }
            float pb[NE]; float ssum = 0.f;
            #pragma unroll
            for (int e = 0; e < NE; ++e) { pb[e] = expf(l[e] - mx); ssum += pb[e]; }
            float inv = 1.f / ssum;
            #pragma unroll
            for (int e = 0; e < NE; ++e) pb[e] *= inv;
            int i1 = 0; float p1 = pb[0];
            #pragma unroll
            for (int e = 1; e < NE; ++e) if (pb[e] > p1) { p1 = pb[e]; i1 = e; }
            int i2 = -1; float p2 = -1.f;
            #pragma unroll
            for (int e = 0; e < NE; ++e) if (e != i1 && pb[e] > p2) { p2 = pb[e]; i2 = e; }
            float denom = p1 + p2 + 1e-8f;
            size_t gt = (size_t)tokid[t];
            out[gt * 2 + 0] = p1 / denom;
            out[gt * 2 + 1] = p2 / denom;
            out[OFF_IDX + gt * 2 + 0] = (float)i1;
            out[OFF_IDX + gt * 2 + 1] = (float)i2;
            #pragma unroll
            for (int e = 0; e < NE; ++e) out[OFF_PROB + gt * 16 + e] = pb[e];
        }
    }
}

// ---------------- fallback router (ws too small): R4-proven on-the-fly bf16 3-term ----------------
__global__ __launch_bounds__(512, 2)
void router_fb(const float* __restrict__ x, const float* __restrict__ W1,
               const float* __restrict__ b1, const float* __restrict__ W2,
               const float* __restrict__ b2, float* __restrict__ out,
               int* __restrict__ cnt, int* __restrict__ list)
{
    __shared__ short xs[BM * 64];
    __shared__ short bs[BN * 64];
    __shared__ float w2t[NE * 128];
    __shared__ float ls[BM * 17];

    float* h_lds = (float*)bs;
    float* lsred = (float*)bs;

    const int tid  = threadIdx.x;
    const int wid  = tid >> 6;
    const int lane = tid & 63;
    const int l31  = lane & 31;
    const int lh   = lane >> 5;
    const int sg   = lane & 7;
    const int wm   = wid >> 2;
    const int wn   = wid & 3;
    const int m0   = blockIdx.x * BM;

    const int tq  = tid & 31;
    const int egq = (tid >> 5) & 3;
    const int ns  = tid >> 7;

    float lacc[4][4];
    #pragma unroll
    for (int i = 0; i < 4; ++i)
        #pragma unroll
        for (int e = 0; e < 4; ++e) lacc[i][e] = 0.f;

    const int arow = tid >> 2, kq = tid & 3;
    const int asig = arow & 7;
    const int nloc = (wid << 6) + lane;
    const int sgl  = lane & 7;

    for (int p = 0; p < NPASS; ++p) {
        f32x16 acc[2][4];
        #pragma unroll
        for (int mf = 0; mf < 2; ++mf)
            #pragma unroll
            for (int nf = 0; nf < 4; ++nf)
                #pragma unroll
                for (int q = 0; q < 16; ++q) acc[mf][nf][q] = 0.f;

        for (int s = 0; s < 64; ++s) {
            __syncthreads();
            {
                const float* wp = W1 + (size_t)(s * 32) * DH + p * BN + nloc;
                short* rb = bs + nloc * 64;
                #pragma unroll
                for (int h = 0; h < 2; ++h) {
                    float f[16];
                    #pragma unroll
                    for (int j = 0; j < 16; ++j)
                        f[j] = wp[(size_t)(h * 16 + j) * DH];
                    uint32_t hd[8], ld_[8];
                    #pragma unroll
                    for (int q = 0; q < 8; ++q) {
                        uint32_t u0 = __float_as_uint(f[2 * q]);
                        uint32_t u1 = __float_as_uint(f[2 * q + 1]);
                        hd[q] = (u0 >> 16) | (u1 & 0xFFFF0000u);
                        float r0 = f[2 * q]     - __uint_as_float(u0 & 0xFFFF0000u);
                        float r1 = f[2 * q + 1] - __uint_as_float(u1 & 0xFFFF0000u);
                        ld_[q] = (__float_as_uint(r0) >> 16) | (__float_as_uint(r1) & 0xFFFF0000u);
                    }
                    *(int4*)(rb + (((2 * h + 0) ^ sgl) << 3)) = make_int4(hd[0], hd[1], hd[2], hd[3]);
                    *(int4*)(rb + (((2 * h + 1) ^ sgl) << 3)) = make_int4(hd[4], hd[5], hd[6], hd[7]);
                    *(int4*)(rb + (((4 + 2 * h + 0) ^ sgl) << 3)) = make_int4(ld_[0], ld_[1], ld_[2], ld_[3]);
                    *(int4*)(rb + (((4 + 2 * h + 1) ^ sgl) << 3)) = make_int4(ld_[4], ld_[5], ld_[6], ld_[7]);
                }
            }
            {
                const float* xp = x + (size_t)(m0 + arow) * DM + s * 32 + kq * 8;
                float4 v0 = *(const float4*)xp;
                float4 v1 = *(const float4*)(xp + 4);
                float f[8] = {v0.x, v0.y, v0.z, v0.w, v1.x, v1.y, v1.z, v1.w};
                uint32_t hd[4], ld_[4];
                #pragma unroll
                for (int q = 0; q < 4; ++q) {
                    uint32_t u0 = __float_as_uint(f[2 * q]);
                    uint32_t u1 = __float_as_uint(f[2 * q + 1]);
                    hd[q] = (u0 >> 16) | (u1 & 0xFFFF0000u);
                    float r0 = f[2 * q]     - __uint_as_float(u0 & 0xFFFF0000u);
                    float r1 = f[2 * q + 1] - __uint_as_float(u1 & 0xFFFF0000u);
                    ld_[q] = (__float_as_uint(r0) >> 16) | (__float_as_uint(r1) & 0xFFFF0000u);
                }
                short* ra = xs + arow * 64;
                *(int4*)(ra + ((kq ^ asig) << 3))       = make_int4(hd[0], hd[1], hd[2], hd[3]);
                *(int4*)(ra + (((4 + kq) ^ asig) << 3)) = make_int4(ld_[0], ld_[1], ld_[2], ld_[3]);
            }
            __syncthreads();
            #pragma unroll
            for (int ks = 0; ks < 2; ++ks) {
                bf16x8 a0[2], a1[2], b0[4], b1f[4];
                #pragma unroll
                for (int mf = 0; mf < 2; ++mf) {
                    int base = (wm * 64 + mf * 32 + l31) * 64;
                    a0[mf] = *(const bf16x8*)(xs + base + (((ks * 2 + lh)) ^ sg) * 8);
                    a1[mf] = *(const bf16x8*)(xs + base + (((4 + ks * 2 + lh)) ^ sg) * 8);
                }
                #pragma unroll
                for (int nf = 0; nf < 4; ++nf) {
                    int base = (wn * 128 + nf * 32 + l31) * 64;
                    b0[nf]  = *(const bf16x8*)(bs + base + (((ks * 2 + lh)) ^ sg) * 8);
                    b1f[nf] = *(const bf16x8*)(bs + base + (((4 + ks * 2 + lh)) ^ sg) * 8);
                }
                #pragma unroll
                for (int mf = 0; mf < 2; ++mf)
                    #pragma unroll
                    for (int nf = 0; nf < 4; ++nf) {
                        acc[mf][nf] = __builtin_amdgcn_mfma_f32_32x32x16_bf16(a0[mf], b0[nf],  acc[mf][nf], 0, 0, 0);
                        acc[mf][nf] = __builtin_amdgcn_mfma_f32_32x32x16_bf16(a0[mf], b1f[nf], acc[mf][nf], 0, 0, 0);
                        acc[mf][nf] = __builtin_amdgcn_mfma_f32_32x32x16_bf16(a1[mf], b0[nf],  acc[mf][nf], 0, 0, 0);
                    }
            }
        }

        for (int ch = 0; ch < 4; ++ch) {
            __syncthreads();
            if (wn == ch) {
                #pragma unroll
                for (int nf = 0; nf < 4; ++nf) {
                    int col = nf * 32 + l31;
                    float bb = b1[p * BN + ch * 128 + col];
                    #pragma unroll
                    for (int mf = 0; mf < 2; ++mf)
                        #pragma unroll
                        for (int r = 0; r < 16; ++r) {
                            int row = wm * 64 + mf * 32 + (r & 3) + 8 * (r >> 2) + 4 * lh;
                            h_lds[row * 128 + col] = fmaxf(acc[mf][nf][r] + bb, 0.f);
                        }
                }
            }
            #pragma unroll
            for (int q = 0; q < 4; ++q) {
                int i = tid * 4 + q;
                int nn = i >> 4, e = i & 15;
                w2t[e * 128 + nn] = W2[(size_t)(p * BN + ch * 128 + nn) * NE + e];
            }
            __syncthreads();
            for (int nn = 0; nn < 32; ++nn) {
                int nL = ns * 32 + ((nn + tq) & 31);
                float hv[4], wv[4];
                #pragma unroll
                for (int i = 0; i < 4; ++i) hv[i] = h_lds[(tq * 4 + i) * 128 + nL];
                #pragma unroll
                for (int e = 0; e < 4; ++e) wv[e] = w2t[(egq * 4 + e) * 128 + nL];
                #pragma unroll
                for (int i = 0; i < 4; ++i)
                    #pragma unroll
                    for (int e = 0; e < 4; ++e)
                        lacc[i][e] = fmaf(hv[i], wv[e], lacc[i][e]);
            }
        }
    }

    __syncthreads();
    #pragma unroll
    for (int i = 0; i < 4; ++i)
        #pragma unroll
        for (int e = 0; e < 4; ++e)
            lsred[((tq * 4 + i) * 16 + egq * 4 + e) * 4 + ns] = lacc[i][e];
    __syncthreads();
    #pragma unroll
    for (int q = 0; q < 4; ++q) {
        int idx = tid * 4 + q;
        int t = idx >> 4, e = idx & 15;
        ls[t * 17 + e] = lsred[idx * 4 + 0] + lsred[idx * 4 + 1] +
                         lsred[idx * 4 + 2] + lsred[idx * 4 + 3] + b2[e];
    }
    __syncthreads();

    if (tid < BM) {
        int t = tid;
        float l[NE]; float mx = -1e30f;
        #pragma unroll
        for (int e = 0; e < NE; ++e) { l[e] = ls[t * 17 + e]; mx = fmaxf(mx, l[e]); }
        float pb[NE]; float ssum = 0.f;
        #pragma unroll
        for (int e = 0; e < NE; ++e) { pb[e] = expf(l[e] - mx); ssum += pb[e]; }
        float inv = 1.f / ssum;
        #pragma unroll
        for (int e = 0; e < NE; ++e) pb[e] *= inv;

        int i1 = 0; float p1 = pb[0];
        #pragma unroll
        for (int e = 1; e < NE; ++e) if (pb[e] > p1) { p1 = pb[e]; i1 = e; }
        int i2 = -1; float p2 = -1.f;
        #pragma unroll
        for (int e = 0; e < NE; ++e) if (e != i1 && pb[e] > p2) { p2 = pb[e]; i2 = e; }
        float p3 = -1.f;
        #pragma unroll
        for (int e = 0; e < NE; ++e) if (e != i1 && e != i2 && pb[e] > p3) p3 = pb[e];

        float denom = p1 + p2 + 1e-8f;
        size_t gt = (size_t)(m0 + t);
        out[gt * 2 + 0] = p1 / denom;
        out[gt * 2 + 1] = p2 / denom;
        out[OFF_IDX + gt * 2 + 0] = (float)i1;
        out[OFF_IDX + gt * 2 + 1] = (float)i2;
        #pragma unroll
        for (int e = 0; e < NE; ++e) out[OFF_PROB + gt * 16 + e] = pb[e];

        if (p1 - p2 < FB_TAU || p2 - p3 < FB_TAU) {
            int k = atomicAdd(cnt, 1);
            list[k] = m0 + t;
        }
    }
}

extern "C" void kernel_launch(void* const* d_in, const int* in_sizes, int n_in,
                              void* d_out, int out_size, void* d_ws, size_t ws_size,
                              hipStream_t stream) {
    const float* x  = (const float*)d_in[0];
    const float* W1 = (const float*)d_in[1];
    const float* b1 = (const float*)d_in[2];
    const float* W2 = (const float*)d_in[3];
    const float* b2 = (const float*)d_in[4];
    float* out = (float*)d_out;

    int*   cnt   = (int*)d_ws;
    int*   list  = (int*)((char*)d_ws + WS_LIST);
    char*  wimg  = (char*)d_ws + WS_WT;
    float* hpart = (float*)wimg;   // repair partials alias wimg (used after router)

    hipMemsetAsync(cnt, 0, sizeof(int), stream);
    if (ws_size >= WS_NEEDED) {
        hipLaunchKernelGGL(prep_w16, dim3(NSTAGE * NPASS), dim3(256), 0, stream, W1, wimg);
        hipLaunchKernelGGL(router16, dim3(TOKENS / BM), dim3(512), 0, stream,
                           x, wimg, b1, W2, b2, out, cnt, list);
        hipLaunchKernelGGL(repair_partial, dim3(512), dim3(256), 0, stream,
                           x, W1, cnt, list, hpart);
        hipLaunchKernelGGL(repair_final, dim3(128), dim3(256), 0, stream,
                           hpart, b1, W2, b2, out, cnt, list);
        // overflow backstop (only runs if nrep > RCAP; expected never)
        hipLaunchKernelGGL(repair4, dim3(512), dim3(256), 0, stream,
                           x, W1, b1, W2, b2, out, cnt, list, RCAP / 4);
    } else {
        hipLaunchKernelGGL(router_fb, dim3(TOKENS / BM), dim3(512), 0, stream,
                           x, W1, b1, W2, b2, out, cnt, list);
        hipLaunchKernelGGL(repair4, dim3(512), dim3(256), 0, stream,
                           x, W1, b1, W2, b2, out, cnt, list, 0);
    }
}